// Round 2
// baseline (2181.464 us; speedup 1.0000x reference)
//
#include <hip/hip_runtime.h>
#include <hip/hip_bf16.h>

// Problem constants
#define B_    8
#define DIM   256
#define HH    160
#define WW_   160
#define NHEAD 8
#define HD    32
#define P_    4
#define WP_   40      // windows per row/col (160/4)
#define NPW   1600    // windows per batch image (40*40)
#define PP    16      // tokens per window (4*4)

// att workspace geometry: rows R = ((b*40+hp)*4+ph)*160 + w  (w-ordered!)
#define NROWS 204800          // 8*40*4*160
#define HSTRIDE 6553600L      // NROWS*32 elements per head plane

typedef __attribute__((ext_vector_type(8))) short bf16x8;
typedef __attribute__((ext_vector_type(4))) float f32x4;

__device__ __forceinline__ unsigned short f2b(float f) {
    __hip_bfloat16 h = __float2bfloat16(f);
    return *(unsigned short*)&h;
}

// Pre-convert out_w (fp32 [256][256]) -> bf16 in workspace (linear [o][k]).
__global__ void convert_w_kernel(const float* __restrict__ w,
                                 short* __restrict__ wb)
{
    const int i = blockIdx.x * 256 + threadIdx.x;   // 16384 threads, 4 elems each
    float4 v = ((const float4*)w)[i];
    short4 o;
    o.x = (short)f2b(v.x); o.y = (short)f2b(v.y);
    o.z = (short)f2b(v.z); o.w = (short)f2b(v.w);
    ((short4*)wb)[i] = o;
}

// ============================================================================
// Phase 1: attention. One block = (b, hp, head, wg) covering 8 windows
// (32 contiguous pixel cols -> 128B-coalesced x loads).
// 128 threads: one (win, pos) task per thread.
// xs layout: [c][r][col ^ (8*r)]  (col-swizzle kills the 4-way q-prep conflict)
// att stores are DENSIFIED via an LDS transpose (reusing xs): each store
// instruction writes 1KB fully-dense per wave (16 complete 64B lines),
// eliminating the partial-line write amplification seen in round 1
// (WRITE_SIZE 651MB for a 105MB buffer).
// ============================================================================
__launch_bounds__(128, 4)
__global__ void attn_kernel(const float* __restrict__ x,
                            const float* __restrict__ qkv_w,
                            const float* __restrict__ qkv_b,
                            const float* __restrict__ pos_encode,
                            const int* __restrict__ pos_index,
                            short* __restrict__ att)
{
    __shared__ float xs[4096];   // [c=32][r=4][colsw=32]; reused as Tu transpose buf
    __shared__ float wqs[32], bqs[32], wks[32], bks[32], wvs[32], bvs[32];
    __shared__ float bias[272];  // [i][j] padded stride 17 -> conflict-free reads

    const int t   = threadIdx.x;
    const int blk = blockIdx.x;
    const int wg  = blk % 5;
    int tmp = blk / 5;
    const int head = tmp & 7; tmp >>= 3;
    const int hp = tmp % 40;
    const int b  = tmp / 40;
    const int c0 = head * 32;
    const int h0 = hp * 4;
    const int w0 = wg * 32;

    if (t < 32) {
        wqs[t] = qkv_w[c0 + t];       bqs[t] = qkv_b[c0 + t];
        wks[t] = qkv_w[256 + c0 + t]; bks[t] = qkv_b[256 + c0 + t];
        wvs[t] = qkv_w[512 + c0 + t]; bvs[t] = qkv_b[512 + c0 + t];
    }
    {
        const int i0 = t >> 4, j0 = t & 15;
        bias[i0 * 17 + j0] = pos_encode[pos_index[t] * 8 + head];
        const int t2 = t + 128;
        const int i1 = t2 >> 4, j1 = t2 & 15;
        bias[i1 * 17 + j1] = pos_encode[pos_index[t2] * 8 + head];
    }

    // Stage x: 1024 float4 tasks; 128B contiguous runs in global.
    // LDS col-swizzle: float4 chunk col4 stored at (col4*4) ^ (r*8).
    #pragma unroll
    for (int it = 0; it < 8; ++it) {
        const int idx  = t + it * 128;         // 0..1023
        const int c    = idx >> 5;             // channel within head
        const int r    = (idx >> 3) & 3;       // patch row
        const int col4 = idx & 7;              // float4 within 32 cols
        const float4 v = *(const float4*)(x +
            (((long)(b * 256 + c0 + c) * 160) + h0 + r) * 160 + w0 + col4 * 4);
        *(float4*)&xs[c * 128 + r * 32 + ((col4 * 4) ^ (r * 8))] = v;
    }
    __syncthreads();

    const int win = t >> 4, i = t & 15;
    const int iph = i >> 2, ipw = i & 3;
    const float scale = 0.17677669529663687f;  // 32^-0.5

    // xs address helper (col swizzle)
    #define XADDR(d_, r_, col_) ((d_) * 128 + (r_) * 32 + ((col_) ^ ((r_) * 8)))

    // q-row prep with wk folded in (2-way bank alias across lanes -> free)
    float qk[32]; float qbk = 0.f;
    #pragma unroll
    for (int d = 0; d < 32; ++d) {
        const float q = (xs[XADDR(d, iph, win * 4 + ipw)] * wqs[d] + bqs[d]) * scale;
        qk[d] = q * wks[d];
        qbk  += q * bks[d];
    }

    // scores + bias (k-row reads are 16-lane LDS broadcasts, 4 distinct banks)
    float s[16];
    #pragma unroll
    for (int j = 0; j < 16; ++j) {
        const int jr = j >> 2, jc = win * 4 + (j & 3);
        float acc = qbk;
        #pragma unroll
        for (int d = 0; d < 32; ++d) acc += qk[d] * xs[XADDR(d, jr, jc)];
        s[j] = acc + bias[i * 17 + j];
    }

    // softmax
    float m = s[0];
    #pragma unroll
    for (int j = 1; j < 16; ++j) m = fmaxf(m, s[j]);
    float l = 0.f;
    #pragma unroll
    for (int j = 0; j < 16; ++j) { s[j] = __expf(s[j] - m); l += s[j]; }
    const float inv = 1.f / l;

    // PV with wv fold; pack to bf16 pairs
    unsigned int ow[16];
    #pragma unroll
    for (int d2 = 0; d2 < 16; ++d2) {
        const int d0 = d2 * 2;
        float a0 = 0.f, a1 = 0.f;
        #pragma unroll
        for (int j = 0; j < 16; ++j) {
            const int jr = j >> 2, jc = win * 4 + (j & 3);
            a0 += s[j] * xs[XADDR(d0,     jr, jc)];
            a1 += s[j] * xs[XADDR(d0 + 1, jr, jc)];
        }
        a0 = a0 * inv * wvs[d0]     + bvs[d0];
        a1 = a1 * inv * wvs[d0 + 1] + bvs[d0 + 1];
        ow[d2] = (unsigned int)f2b(a0) | ((unsigned int)f2b(a1) << 16);
    }
    #undef XADDR

    // ---- Dense store: transpose through LDS (reuse xs), then 16B/lane
    // stores covering 1KB contiguous per wave per instruction. ----
    __syncthreads();                        // xs reads done
    unsigned int* Tu = (unsigned int*)xs;   // [rowid][20] uints (80B, 16B-aligned)
    {
        const int tb = (iph * 32 + win * 4 + ipw) * 20;
        uint4 v0 = {ow[0],  ow[1],  ow[2],  ow[3]};
        uint4 v1 = {ow[4],  ow[5],  ow[6],  ow[7]};
        uint4 v2 = {ow[8],  ow[9],  ow[10], ow[11]};
        uint4 v3 = {ow[12], ow[13], ow[14], ow[15]};
        *(uint4*)&Tu[tb +  0] = v0;
        *(uint4*)&Tu[tb +  4] = v1;
        *(uint4*)&Tu[tb +  8] = v2;
        *(uint4*)&Tu[tb + 12] = v3;
    }
    __syncthreads();
    {
        short* dstB = att + (long)head * HSTRIDE
                          + ((long)((b * 40 + hp) * 4) * 160 + w0) * 32;
        #pragma unroll
        for (int k2 = 0; k2 < 4; ++k2) {       // k2 == iph region (2KB each)
            const int rr = k2 * 32 + (t >> 2);
            uint4 v = *(const uint4*)&Tu[rr * 20 + (t & 3) * 4];
            *(uint4*)(dstB + (long)k2 * (160 * 32) + t * 8) = v;
        }
    }
}

// ============================================================================
// Phase 2: 1x1 conv as GEMM, computing Y^T tiles: D[o][w] so the lane-fast
// D dim is w -> coalesced stores. A = W in swizzled LDS (shared by all 4
// waves -> frees ~128 VGPRs vs reg-resident, doubling occupancy), B = att
// from workspace (1KB fully-coalesced fragment loads).
// ============================================================================
__launch_bounds__(256, 4)
__global__ void conv_kernel(const short* __restrict__ att,
                            const short* __restrict__ wb,
                            float* __restrict__ y)
{
    __shared__ short wlds[64 * 256];   // 32 KB, rows XOR-swizzled (^((row&7)<<4))

    const int blk = blockIdx.x;
    // blk = sh*32 + og*8 + sl ; s = sh*8 + sl  (og-blocks of a strip share an XCD)
    const int sl = blk & 7;
    const int og = (blk >> 3) & 3;
    const int sh = blk >> 5;
    const int s  = sh * 8 + sl;          // 0..319
    const int b  = s / 40;
    const int hp = s % 40;

    const int t    = threadIdx.x;
    const int ph   = t >> 6;             // wave id = patch row
    const int lane = t & 63;
    const int m16  = lane & 15;
    const int kq   = lane >> 4;

    // Stage W tile (64 o x 256 k bf16 = 32 KB) with write-side swizzle.
    {
        const char* wsrc = (const char*)(wb + og * 64 * 256);
        #pragma unroll
        for (int it = 0; it < 8; ++it) {
            const int byteoff = (t + it * 256) * 16;     // 0..32752
            const int row = byteoff >> 9;                // 512B rows
            const int swz = byteoff ^ ((row & 7) << 4);
            uint4 v = *(const uint4*)(wsrc + byteoff);
            *(uint4*)((char*)wlds + swz) = v;
        }
    }
    __syncthreads();

    // W fragment read (swizzled): row = nt*16+m16, bytes kk*64 + kq*16
    #define WF(nt_, kk_) (*(const bf16x8*)((const char*)wlds + \
        ((((nt_) * 16 + m16) * 512 + (kk_) * 64 + kq * 16) ^ ((m16 & 7) << 4))))

    const int  R0   = s * 640 + ph * 160;         // strip row base for this wave
    const short* arow = att + (long)(R0 + m16) * 32 + kq * 8;  // + kk*HSTRIDE + cc*512
    float* yo = y + ((long)(b * 256 + og * 64) * 160 + (hp * 4 + ph)) * 160;

    const f32x4 zf = {0.f, 0.f, 0.f, 0.f};
    bf16x8 bA[8], bB[8];

#define LB(dstb, cc_) { \
    _Pragma("unroll") \
    for (int kk = 0; kk < 8; ++kk) \
        dstb[kk] = *(const bf16x8*)(arow + kk * HSTRIDE + (cc_) * 512); }

#define COMP(bfb, cc_) { \
    f32x4 a0 = zf, a1 = zf, a2 = zf, a3 = zf; \
    _Pragma("unroll") \
    for (int kk = 0; kk < 8; ++kk) { \
        bf16x8 w0 = WF(0, kk), w1 = WF(1, kk), w2 = WF(2, kk), w3 = WF(3, kk); \
        a0 = __builtin_amdgcn_mfma_f32_16x16x32_bf16(w0, bfb[kk], a0, 0, 0, 0); \
        a1 = __builtin_amdgcn_mfma_f32_16x16x32_bf16(w1, bfb[kk], a1, 0, 0, 0); \
        a2 = __builtin_amdgcn_mfma_f32_16x16x32_bf16(w2, bfb[kk], a2, 0, 0, 0); \
        a3 = __builtin_amdgcn_mfma_f32_16x16x32_bf16(w3, bfb[kk], a3, 0, 0, 0); \
    } \
    _Pragma("unroll") \
    for (int r = 0; r < 4; ++r) { \
        const int oo = kq * 4 + r; \
        yo[(long)(oo     ) * 25600 + (cc_) * 16 + m16] = a0[r]; \
        yo[(long)(oo + 16) * 25600 + (cc_) * 16 + m16] = a1[r]; \
        yo[(long)(oo + 32) * 25600 + (cc_) * 16 + m16] = a2[r]; \
        yo[(long)(oo + 48) * 25600 + (cc_) * 16 + m16] = a3[r]; \
    } }

    LB(bA, 0);
    #pragma unroll
    for (int c2 = 0; c2 < 5; ++c2) {
        LB(bB, 2 * c2 + 1);
        COMP(bA, 2 * c2);
        if (c2 < 4) LB(bA, 2 * c2 + 2);
        COMP(bB, 2 * c2 + 1);
    }
#undef LB
#undef COMP
#undef WF
}

extern "C" void kernel_launch(void* const* d_in, const int* in_sizes, int n_in,
                              void* d_out, int out_size, void* d_ws, size_t ws_size,
                              hipStream_t stream) {
    const float* x          = (const float*)d_in[0];
    const float* qkv_w      = (const float*)d_in[1];
    const float* qkv_b      = (const float*)d_in[2];
    const float* pos_encode = (const float*)d_in[3];
    const float* out_w      = (const float*)d_in[4];
    const int*   pos_index  = (const int*)d_in[5];
    float* y = (float*)d_out;
    short* w_bf16 = (short*)d_ws;
    short* att = w_bf16 + 65536;   // after the 128KB bf16 W

    convert_w_kernel<<<dim3(64), dim3(256), 0, stream>>>(out_w, w_bf16);
    attn_kernel<<<dim3(12800), dim3(128), 0, stream>>>(
        x, qkv_w, qkv_b, pos_encode, pos_index, att);
    conv_kernel<<<dim3(1280), dim3(256), 0, stream>>>(att, w_bf16, y);
}

// Round 3
// 1299.519 us; speedup vs baseline: 1.6787x; 1.6787x over previous
//
#include <hip/hip_runtime.h>
#include <hip/hip_bf16.h>

// Problem constants
#define B_    8
#define DIM   256
#define HH    160
#define WW_   160
#define NHEAD 8
#define HD    32
#define P_    4
#define WP_   40      // windows per row/col (160/4)
#define NPW   1600    // windows per batch image (40*40)
#define PP    16      // tokens per window (4*4)

// att workspace geometry: rows R = ((b*40+hp)*4+ph)*160 + w  (w-ordered!)
#define NROWS 204800          // 8*40*4*160
#define HSTRIDE 6553600L      // NROWS*32 elements per head plane

typedef __attribute__((ext_vector_type(8))) short bf16x8;
typedef __attribute__((ext_vector_type(4))) float f32x4;

__device__ __forceinline__ unsigned short f2b(float f) {
    __hip_bfloat16 h = __float2bfloat16(f);
    return *(unsigned short*)&h;
}

// Pre-convert out_w (fp32 [256][256]) -> bf16 in workspace (linear [o][k]).
__global__ void convert_w_kernel(const float* __restrict__ w,
                                 short* __restrict__ wb)
{
    const int i = blockIdx.x * 256 + threadIdx.x;   // 16384 threads, 4 elems each
    float4 v = ((const float4*)w)[i];
    short4 o;
    o.x = (short)f2b(v.x); o.y = (short)f2b(v.y);
    o.z = (short)f2b(v.z); o.w = (short)f2b(v.w);
    ((short4*)wb)[i] = o;
}

// ============================================================================
// Phase 1: attention. One block = (b, hp, head, wg) covering 8 windows
// (32 contiguous pixel cols -> 128B-coalesced x loads).
// 128 threads: one (win, pos) task per thread.
// xs layout: [c][r][col ^ (8*r)]  (col-swizzle kills the 4-way q-prep conflict)
// att stores DENSIFIED via LDS transpose: 16B/lane, 1KB/wave fully-dense.
// NOTE: __launch_bounds__ MUST stay (128, 2): the body needs ~128 VGPRs of
// live state (qk[32]+s[16]+ow[16]); (128,4) capped VGPRs at 64 and spilled
// 6.3 GB/dispatch to scratch (round-2 regression).
// ============================================================================
__launch_bounds__(128, 2)
__global__ void attn_kernel(const float* __restrict__ x,
                            const float* __restrict__ qkv_w,
                            const float* __restrict__ qkv_b,
                            const float* __restrict__ pos_encode,
                            const int* __restrict__ pos_index,
                            short* __restrict__ att)
{
    __shared__ float xs[4096];   // [c=32][r=4][colsw=32]; reused as Tu transpose buf
    __shared__ float wqs[32], bqs[32], wks[32], bks[32], wvs[32], bvs[32];
    __shared__ float bias[272];  // [i][j] padded stride 17 -> conflict-free reads

    const int t   = threadIdx.x;
    const int blk = blockIdx.x;
    const int wg  = blk % 5;
    int tmp = blk / 5;
    const int head = tmp & 7; tmp >>= 3;
    const int hp = tmp % 40;
    const int b  = tmp / 40;
    const int c0 = head * 32;
    const int h0 = hp * 4;
    const int w0 = wg * 32;

    if (t < 32) {
        wqs[t] = qkv_w[c0 + t];       bqs[t] = qkv_b[c0 + t];
        wks[t] = qkv_w[256 + c0 + t]; bks[t] = qkv_b[256 + c0 + t];
        wvs[t] = qkv_w[512 + c0 + t]; bvs[t] = qkv_b[512 + c0 + t];
    }
    {
        const int i0 = t >> 4, j0 = t & 15;
        bias[i0 * 17 + j0] = pos_encode[pos_index[t] * 8 + head];
        const int t2 = t + 128;
        const int i1 = t2 >> 4, j1 = t2 & 15;
        bias[i1 * 17 + j1] = pos_encode[pos_index[t2] * 8 + head];
    }

    // Stage x: 1024 float4 tasks; 128B contiguous runs in global.
    // LDS col-swizzle: float4 chunk col4 stored at (col4*4) ^ (r*8).
    #pragma unroll
    for (int it = 0; it < 8; ++it) {
        const int idx  = t + it * 128;         // 0..1023
        const int c    = idx >> 5;             // channel within head
        const int r    = (idx >> 3) & 3;       // patch row
        const int col4 = idx & 7;              // float4 within 32 cols
        const float4 v = *(const float4*)(x +
            (((long)(b * 256 + c0 + c) * 160) + h0 + r) * 160 + w0 + col4 * 4);
        *(float4*)&xs[c * 128 + r * 32 + ((col4 * 4) ^ (r * 8))] = v;
    }
    __syncthreads();

    const int win = t >> 4, i = t & 15;
    const int iph = i >> 2, ipw = i & 3;
    const float scale = 0.17677669529663687f;  // 32^-0.5

    // xs address helper (col swizzle)
    #define XADDR(d_, r_, col_) ((d_) * 128 + (r_) * 32 + ((col_) ^ ((r_) * 8)))

    // q-row prep with wk folded in (2-way bank alias across lanes -> free)
    float qk[32]; float qbk = 0.f;
    #pragma unroll
    for (int d = 0; d < 32; ++d) {
        const float q = (xs[XADDR(d, iph, win * 4 + ipw)] * wqs[d] + bqs[d]) * scale;
        qk[d] = q * wks[d];
        qbk  += q * bks[d];
    }

    // scores + bias (k-row reads are 16-lane LDS broadcasts, 4 distinct banks)
    float s[16];
    #pragma unroll
    for (int j = 0; j < 16; ++j) {
        const int jr = j >> 2, jc = win * 4 + (j & 3);
        float acc = qbk;
        #pragma unroll
        for (int d = 0; d < 32; ++d) acc += qk[d] * xs[XADDR(d, jr, jc)];
        s[j] = acc + bias[i * 17 + j];
    }

    // softmax
    float m = s[0];
    #pragma unroll
    for (int j = 1; j < 16; ++j) m = fmaxf(m, s[j]);
    float l = 0.f;
    #pragma unroll
    for (int j = 0; j < 16; ++j) { s[j] = __expf(s[j] - m); l += s[j]; }
    const float inv = 1.f / l;

    // PV with wv fold; pack to bf16 pairs
    unsigned int ow[16];
    #pragma unroll
    for (int d2 = 0; d2 < 16; ++d2) {
        const int d0 = d2 * 2;
        float a0 = 0.f, a1 = 0.f;
        #pragma unroll
        for (int j = 0; j < 16; ++j) {
            const int jr = j >> 2, jc = win * 4 + (j & 3);
            a0 += s[j] * xs[XADDR(d0,     jr, jc)];
            a1 += s[j] * xs[XADDR(d0 + 1, jr, jc)];
        }
        a0 = a0 * inv * wvs[d0]     + bvs[d0];
        a1 = a1 * inv * wvs[d0 + 1] + bvs[d0 + 1];
        ow[d2] = (unsigned int)f2b(a0) | ((unsigned int)f2b(a1) << 16);
    }
    #undef XADDR

    // ---- Dense store: transpose through LDS (reuse xs), then 16B/lane
    // stores covering 1KB contiguous per wave per instruction. ----
    __syncthreads();                        // xs reads done
    unsigned int* Tu = (unsigned int*)xs;   // [rowid][20] uints (80B, 16B-aligned)
    {
        const int tb = (iph * 32 + win * 4 + ipw) * 20;
        uint4 v0 = {ow[0],  ow[1],  ow[2],  ow[3]};
        uint4 v1 = {ow[4],  ow[5],  ow[6],  ow[7]};
        uint4 v2 = {ow[8],  ow[9],  ow[10], ow[11]};
        uint4 v3 = {ow[12], ow[13], ow[14], ow[15]};
        *(uint4*)&Tu[tb +  0] = v0;
        *(uint4*)&Tu[tb +  4] = v1;
        *(uint4*)&Tu[tb +  8] = v2;
        *(uint4*)&Tu[tb + 12] = v3;
    }
    __syncthreads();
    {
        short* dstB = att + (long)head * HSTRIDE
                          + ((long)((b * 40 + hp) * 4) * 160 + w0) * 32;
        #pragma unroll
        for (int k2 = 0; k2 < 4; ++k2) {       // k2 == iph region (2KB each)
            const int rr = k2 * 32 + (t >> 2);
            uint4 v = *(const uint4*)&Tu[rr * 20 + (t & 3) * 4];
            *(uint4*)(dstB + (long)k2 * (160 * 32) + t * 8) = v;
        }
    }
}

// ============================================================================
// Phase 2: 1x1 conv as GEMM, computing Y^T tiles: D[o][w] so the lane-fast
// D dim is w -> coalesced stores. A = W in swizzled LDS (shared by all 4
// waves), B = att from workspace (1KB fully-coalesced fragment loads).
// ============================================================================
__launch_bounds__(256, 4)
__global__ void conv_kernel(const short* __restrict__ att,
                            const short* __restrict__ wb,
                            float* __restrict__ y)
{
    __shared__ short wlds[64 * 256];   // 32 KB, rows XOR-swizzled (^((row&7)<<4))

    const int blk = blockIdx.x;
    // blk = sh*32 + og*8 + sl ; s = sh*8 + sl  (og-blocks of a strip share an XCD)
    const int sl = blk & 7;
    const int og = (blk >> 3) & 3;
    const int sh = blk >> 5;
    const int s  = sh * 8 + sl;          // 0..319
    const int b  = s / 40;
    const int hp = s % 40;

    const int t    = threadIdx.x;
    const int ph   = t >> 6;             // wave id = patch row
    const int lane = t & 63;
    const int m16  = lane & 15;
    const int kq   = lane >> 4;

    // Stage W tile (64 o x 256 k bf16 = 32 KB) with write-side swizzle.
    {
        const char* wsrc = (const char*)(wb + og * 64 * 256);
        #pragma unroll
        for (int it = 0; it < 8; ++it) {
            const int byteoff = (t + it * 256) * 16;     // 0..32752
            const int row = byteoff >> 9;                // 512B rows
            const int swz = byteoff ^ ((row & 7) << 4);
            uint4 v = *(const uint4*)(wsrc + byteoff);
            *(uint4*)((char*)wlds + swz) = v;
        }
    }
    __syncthreads();

    // W fragment read (swizzled): row = nt*16+m16, bytes kk*64 + kq*16
    #define WF(nt_, kk_) (*(const bf16x8*)((const char*)wlds + \
        ((((nt_) * 16 + m16) * 512 + (kk_) * 64 + kq * 16) ^ ((m16 & 7) << 4))))

    const int  R0   = s * 640 + ph * 160;         // strip row base for this wave
    const short* arow = att + (long)(R0 + m16) * 32 + kq * 8;  // + kk*HSTRIDE + cc*512
    float* yo = y + ((long)(b * 256 + og * 64) * 160 + (hp * 4 + ph)) * 160;

    const f32x4 zf = {0.f, 0.f, 0.f, 0.f};
    bf16x8 bA[8], bB[8];

#define LB(dstb, cc_) { \
    _Pragma("unroll") \
    for (int kk = 0; kk < 8; ++kk) \
        dstb[kk] = *(const bf16x8*)(arow + kk * HSTRIDE + (cc_) * 512); }

#define COMP(bfb, cc_) { \
    f32x4 a0 = zf, a1 = zf, a2 = zf, a3 = zf; \
    _Pragma("unroll") \
    for (int kk = 0; kk < 8; ++kk) { \
        bf16x8 w0 = WF(0, kk), w1 = WF(1, kk), w2 = WF(2, kk), w3 = WF(3, kk); \
        a0 = __builtin_amdgcn_mfma_f32_16x16x32_bf16(w0, bfb[kk], a0, 0, 0, 0); \
        a1 = __builtin_amdgcn_mfma_f32_16x16x32_bf16(w1, bfb[kk], a1, 0, 0, 0); \
        a2 = __builtin_amdgcn_mfma_f32_16x16x32_bf16(w2, bfb[kk], a2, 0, 0, 0); \
        a3 = __builtin_amdgcn_mfma_f32_16x16x32_bf16(w3, bfb[kk], a3, 0, 0, 0); \
    } \
    _Pragma("unroll") \
    for (int r = 0; r < 4; ++r) { \
        const int oo = kq * 4 + r; \
        yo[(long)(oo     ) * 25600 + (cc_) * 16 + m16] = a0[r]; \
        yo[(long)(oo + 16) * 25600 + (cc_) * 16 + m16] = a1[r]; \
        yo[(long)(oo + 32) * 25600 + (cc_) * 16 + m16] = a2[r]; \
        yo[(long)(oo + 48) * 25600 + (cc_) * 16 + m16] = a3[r]; \
    } }

    LB(bA, 0);
    #pragma unroll
    for (int c2 = 0; c2 < 5; ++c2) {
        LB(bB, 2 * c2 + 1);
        COMP(bA, 2 * c2);
        if (c2 < 4) LB(bA, 2 * c2 + 2);
        COMP(bB, 2 * c2 + 1);
    }
#undef LB
#undef COMP
#undef WF
}

extern "C" void kernel_launch(void* const* d_in, const int* in_sizes, int n_in,
                              void* d_out, int out_size, void* d_ws, size_t ws_size,
                              hipStream_t stream) {
    const float* x          = (const float*)d_in[0];
    const float* qkv_w      = (const float*)d_in[1];
    const float* qkv_b      = (const float*)d_in[2];
    const float* pos_encode = (const float*)d_in[3];
    const float* out_w      = (const float*)d_in[4];
    const int*   pos_index  = (const int*)d_in[5];
    float* y = (float*)d_out;
    short* w_bf16 = (short*)d_ws;
    short* att = w_bf16 + 65536;   // after the 128KB bf16 W

    convert_w_kernel<<<dim3(64), dim3(256), 0, stream>>>(out_w, w_bf16);
    attn_kernel<<<dim3(12800), dim3(128), 0, stream>>>(
        x, qkv_w, qkv_b, pos_encode, pos_index, att);
    conv_kernel<<<dim3(1280), dim3(256), 0, stream>>>(att, w_bf16, y);
}